// Round 17
// baseline (87.160 us; speedup 1.0000x reference)
//
#include <hip/hip_runtime.h>

// ---------------------------------------------------------------------------
// PYG_GCN: y = relu(x@W_in+b_in) -> GCNConv(W_gcn,b_gcn) -> relu -> @W_cls+b_cls
// N=50000, E=600000, D=128, C=40.
// R17 = R16 with a 4-pass column-sliced gather in aggout: each pass touches a
// 3.2MB xws slice (fits 4MiB per-XCD L2) -> random gathers served from L2.
// Per-edge dinv staged in LDS once. Rest identical.
// ---------------------------------------------------------------------------

typedef __bf16 bf16x8 __attribute__((ext_vector_type(8)));
typedef float f32x4 __attribute__((ext_vector_type(4)));

#define NBUCK 512      // bucket = col>>7; used 0..390 for N=50000
#define CH_MAX 4704    // max edges per sort-chunk block
#define PREP_BLKS 76   // 38912 weight elements / 512
#define SCAP 1024      // aggout LDS edge window (32 nodes: mean 384, +32 sigma)

__device__ __forceinline__ ushort f2b(float f) {  // fp32 -> bf16 RNE
  uint u = __float_as_uint(f);
  return (ushort)((u + 0x7FFFu + ((u >> 16) & 1u)) >> 16);
}
__device__ __forceinline__ float b2f_lo(uint u) { return __uint_as_float(u << 16); }
__device__ __forceinline__ float b2f_hi(uint u) { return __uint_as_float(u & 0xFFFF0000u); }

// ---------------- fused GEMM1+2 tile: 512 threads, 128 rows ----------------
// xws = (relu(x@Wti^T + b_in)) @ Wtg^T   (h lives only in LDS; unscaled out)
__device__ __forceinline__ void g12_tile_512(const float* __restrict__ x,
                                             const ushort* __restrict__ Wti,
                                             const ushort* __restrict__ Wtg,
                                             const float* __restrict__ b_in,
                                             ushort* __restrict__ xws,
                                             int nrows, int row0,
                                             char* smem, int tid) {
  ushort (*As)[136] = (ushort(*)[136])smem;                    // 128 rows
  ushort (*Bs)[136] = (ushort(*)[136])(smem + 128 * 136 * 2);  // 128 rows
#pragma unroll
  for (int q = 0; q < 4; ++q) {
    int f = tid + 512 * q;
    int r = f >> 4, cw = f & 15;
    *(uint4*)&Bs[r][cw * 8] = *(const uint4*)&Wti[r * 128 + cw * 8];
  }
#pragma unroll
  for (int q = 0; q < 8; ++q) {
    int f = tid + 512 * q;
    int r = f >> 5, kc = f & 31;
    float4 v = make_float4(0.f, 0.f, 0.f, 0.f);
    if (row0 + r < nrows) v = *(const float4*)&x[(size_t)(row0 + r) * 128 + kc * 4];
    ushort4 o;
    o.x = f2b(v.x); o.y = f2b(v.y); o.z = f2b(v.z); o.w = f2b(v.w);
    *(ushort4*)&As[r][kc * 4] = o;
  }
  __syncthreads();

  const int wid = tid >> 6, lane = tid & 63;
  const int fr = lane & 15, fg = lane >> 4;
  f32x4 acc[8];
#pragma unroll
  for (int nn = 0; nn < 8; ++nn) acc[nn] = (f32x4){0.f, 0.f, 0.f, 0.f};
#pragma unroll
  for (int ks = 0; ks < 4; ++ks) {
    const int kb = ks * 32 + fg * 8;
    bf16x8 a = *(const bf16x8*)&As[wid * 16 + fr][kb];
#pragma unroll
    for (int nn = 0; nn < 8; ++nn) {
      bf16x8 b = *(const bf16x8*)&Bs[nn * 16 + fr][kb];
      acc[nn] = __builtin_amdgcn_mfma_f32_16x16x32_bf16(a, b, acc[nn], 0, 0, 0);
    }
  }
  __syncthreads();  // all stage-1 reads done

  // h = relu(acc + b_in) -> bf16 back into As (D-frag layout); restage Wtg
#pragma unroll
  for (int nn = 0; nn < 8; ++nn) {
    const int cn = nn * 16 + fr;
    const float bv = b_in[cn];
#pragma unroll
    for (int i = 0; i < 4; ++i)
      As[wid * 16 + fg * 4 + i][cn] = f2b(fmaxf(acc[nn][i] + bv, 0.f));
  }
#pragma unroll
  for (int q = 0; q < 4; ++q) {
    int f = tid + 512 * q;
    int r = f >> 4, cw = f & 15;
    *(uint4*)&Bs[r][cw * 8] = *(const uint4*)&Wtg[r * 128 + cw * 8];
  }
  __syncthreads();

  f32x4 acc2[8];
#pragma unroll
  for (int nn = 0; nn < 8; ++nn) acc2[nn] = (f32x4){0.f, 0.f, 0.f, 0.f};
#pragma unroll
  for (int ks = 0; ks < 4; ++ks) {
    const int kb = ks * 32 + fg * 8;
    bf16x8 a = *(const bf16x8*)&As[wid * 16 + fr][kb];
#pragma unroll
    for (int nn = 0; nn < 8; ++nn) {
      bf16x8 b = *(const bf16x8*)&Bs[nn * 16 + fr][kb];
      acc2[nn] = __builtin_amdgcn_mfma_f32_16x16x32_bf16(a, b, acc2[nn], 0, 0, 0);
    }
  }
  const int r0 = row0 + wid * 16 + fg * 4;
#pragma unroll
  for (int nn = 0; nn < 8; ++nn) {
    const int cn = nn * 16 + fr;
#pragma unroll
    for (int i = 0; i < 4; ++i) {
      const int rr = r0 + i;
      if (rr < nrows) xws[(size_t)rr * 128 + cn] = f2b(acc2[nn][i]);
    }
  }
}

// ---------------- L1: weight prep [0,76) || coarse chist -------------------
__global__ __launch_bounds__(512) void k_L1_prep_chist(const float* __restrict__ Wi,
                                                       const float* __restrict__ Wg,
                                                       const float* __restrict__ Wc,
                                                       ushort* __restrict__ Ti,
                                                       ushort* __restrict__ Tg,
                                                       ushort* __restrict__ Tc,
                                                       const int* __restrict__ col,
                                                       int* __restrict__ H2,
                                                       int E, int chunk, int sortb) {
  __shared__ int hist[NBUCK];
  const int tid = threadIdx.x;
  if (blockIdx.x < PREP_BLKS) {
    int idx = blockIdx.x * 512 + tid;
    if (idx < 16384) {
      int c = idx >> 7, k = idx & 127;
      Ti[c * 128 + k] = f2b(Wi[k * 128 + c]);
    } else if (idx < 32768) {
      int j = idx - 16384;
      int c = j >> 7, k = j & 127;
      Tg[c * 128 + k] = f2b(Wg[k * 128 + c]);
    } else if (idx < 38912) {
      int j = idx - 32768;
      int c = j >> 7, k = j & 127;
      Tc[c * 128 + k] = (c < 40) ? f2b(Wc[k * 40 + c]) : (ushort)0;
    }
    return;
  }
  const int blk = blockIdx.x - PREP_BLKS;
  if (tid < NBUCK) hist[tid] = 0;
  __syncthreads();
  const int e0 = blk * chunk;
  const int cnt = min(chunk, E - e0);
  for (int i = tid; i < cnt; i += 512)
    atomicAdd(&hist[((unsigned)col[e0 + i]) >> 7], 1);
  __syncthreads();
  if (tid < NBUCK) H2[tid * sortb + blk] = hist[tid];
}

// ---------------- L2: block 0 = bucket scan; blocks 1.. = G12 tiles [0,T1) -
__global__ __launch_bounds__(512) void k_L2_scan_g12(const int* __restrict__ H2,
                                                     int* __restrict__ Hs,
                                                     int* __restrict__ cursor,
                                                     int sortb,
                                                     const float* __restrict__ x,
                                                     const ushort* __restrict__ Wti,
                                                     const ushort* __restrict__ Wtg,
                                                     const float* __restrict__ b_in,
                                                     ushort* __restrict__ xws,
                                                     int nrows) {
  __shared__ __align__(16) char smem[69632];
  const int tid = threadIdx.x;
  if (blockIdx.x == 0) {
    int* sd = (int*)smem;  // 512 ints
    int s = 0;
    const int4* p = (const int4*)&H2[tid * sortb];
    for (int j = 0; j < sortb / 4; ++j) { int4 v = p[j]; s += v.x + v.y + v.z + v.w; }
    sd[tid] = s;
    __syncthreads();
    for (int off = 1; off < 512; off <<= 1) {
      int u = (tid >= off) ? sd[tid - off] : 0;
      __syncthreads();
      sd[tid] += u;
      __syncthreads();
    }
    Hs[tid] = sd[tid] - s;          // exclusive
    if (tid == 511) Hs[NBUCK] = sd[511];
    cursor[tid] = 0;
    return;
  }
  g12_tile_512(x, Wti, Wtg, b_in, xws, nrows, (blockIdx.x - 1) * 128, smem, tid);
}

// ---------------- L3: reorder [0,sortb) || G12 tiles [T1,T2) ---------------
// ebuf record: (c_local<<16) | row  (row < 65536 since N=50000).
__global__ __launch_bounds__(512) void k_L3_reorder_g12(const int* __restrict__ row,
                                                        const int* __restrict__ col,
                                                        const int* __restrict__ Hs,
                                                        int* __restrict__ cursor,
                                                        uint* __restrict__ ebuf,
                                                        int E, int chunk, int sortb,
                                                        const float* __restrict__ x,
                                                        const ushort* __restrict__ Wti,
                                                        const ushort* __restrict__ Wtg,
                                                        const float* __restrict__ b_in,
                                                        ushort* __restrict__ xws,
                                                        int nrows, int tile0) {
  __shared__ __align__(16) char smem[69632];
  const int tid = threadIdx.x;
  if (blockIdx.x < (unsigned)sortb) {
    int* hist   = (int*)smem;              // NBUCK
    int* lstart = hist + NBUCK;            // NBUCK
    int* cnt2   = lstart + NBUCK;          // NBUCK
    int* obase  = cnt2 + NBUCK;            // NBUCK
    uint* data  = (uint*)(obase + NBUCK);  // CH_MAX
    int* gpos   = (int*)(data + CH_MAX);   // CH_MAX
    int* sd     = gpos + CH_MAX;           // 512
    hist[tid] = 0; cnt2[tid] = 0;
    __syncthreads();
    const int e0 = blockIdx.x * chunk;
    const int cnt = min(chunk, E - e0);
    for (int i = tid; i < cnt; i += 512)
      atomicAdd(&hist[((unsigned)col[e0 + i]) >> 7], 1);
    __syncthreads();
    const int h0 = hist[tid];
    sd[tid] = h0;
    __syncthreads();
    for (int off = 1; off < 512; off <<= 1) {
      int u = (tid >= off) ? sd[tid - off] : 0;
      __syncthreads();
      sd[tid] += u;
      __syncthreads();
    }
    lstart[tid] = sd[tid] - h0;
    obase[tid] = Hs[tid] + (h0 ? atomicAdd(&cursor[tid], h0) : 0);
    __syncthreads();
    for (int i = tid; i < cnt; i += 512) {
      const int c = col[e0 + i], r = row[e0 + i];
      const int b = ((unsigned)c) >> 7;
      const int rk = atomicAdd(&cnt2[b], 1);
      const int slot = lstart[b] + rk;
      data[slot] = ((uint)(c & 127) << 16) | (uint)r;
      gpos[slot] = obase[b] + rk;
    }
    __syncthreads();
    for (int i = tid; i < cnt; i += 512)
      ebuf[gpos[i]] = data[i];
    return;
  }
  g12_tile_512(x, Wti, Wtg, b_in, xws, nrows,
               (tile0 + (int)blockIdx.x - sortb) * 128, smem, tid);
}

// ---------------- L4: sort2 [0,nbuck) || G12 tiles [T2,NT) -----------------
// P[node] = END offset (seg = [P[c-1], P[c]), P[-1] := 0).
__global__ __launch_bounds__(512) void k_L4_sort_g12(const uint* __restrict__ ebuf,
                                                     const int* __restrict__ Hs,
                                                     int* __restrict__ srcrow,
                                                     int* __restrict__ P,
                                                     float* __restrict__ dinv,
                                                     int nbuck,
                                                     const float* __restrict__ x,
                                                     const ushort* __restrict__ Wti,
                                                     const ushort* __restrict__ Wtg,
                                                     const float* __restrict__ b_in,
                                                     ushort* __restrict__ xws,
                                                     int n, int tile0) {
  __shared__ __align__(16) char smem[69632];
  const int tid = threadIdx.x;
  if (blockIdx.x < (unsigned)nbuck) {
    int* cnt    = (int*)smem;        // 128
    int* lstart = cnt + 128;         // 128
    int* cnt2   = lstart + 128;      // 128
    int* sd     = cnt2 + 128;        // 512
    if (tid < 128) { cnt[tid] = 0; cnt2[tid] = 0; }
    __syncthreads();
    const int b = blockIdx.x;
    const int start = Hs[b];
    const int end = Hs[b + 1];
    for (int i = start + tid; i < end; i += 512)
      atomicAdd(&cnt[ebuf[i] >> 16], 1);
    __syncthreads();
    const int cv = (tid < 128) ? cnt[tid] : 0;
    sd[tid] = cv;
    __syncthreads();
    for (int off = 1; off < 128; off <<= 1) {
      int u = (tid >= off) ? sd[tid - off] : 0;
      __syncthreads();
      sd[tid] += u;
      __syncthreads();
    }
    if (tid < 128) {
      const int ex = sd[tid] - cv;
      lstart[tid] = ex;
      const int node = b * 128 + tid;
      if (node < n) {
        P[node] = start + ex + cv;
        dinv[node] = rsqrtf((float)cv + 1.0f);
      }
    }
    __syncthreads();
    for (int i = start + tid; i < end; i += 512) {
      const uint v = ebuf[i];
      const int c = v >> 16;
      const int rk = atomicAdd(&cnt2[c], 1);
      srcrow[start + lstart[c] + rk] = (int)(v & 0xFFFFu);
    }
    return;
  }
  g12_tile_512(x, Wti, Wtg, b_in, xws, n,
               (tile0 + (int)blockIdx.x - nbuck) * 128, smem, tid);
}

// ---------------- L5: fused aggregate + classifier -------------------------
// 512 threads / 32 nodes. 4-pass column-sliced gather: pass p touches xws
// cols [32p,32p+32) only (3.2MB slice, fits per-XCD L2). Static quarter-per-
// node; per-edge dinv staged in LDS once. Then 6-wave 32x128x48 MFMA.
__global__ __launch_bounds__(512) void k_aggout(const int* __restrict__ P,
                                                const int* __restrict__ srcrow,
                                                const ushort* __restrict__ xws,
                                                const float* __restrict__ dinv,
                                                const float* __restrict__ b_gcn,
                                                const ushort* __restrict__ Wtc,
                                                const float* __restrict__ bc,
                                                float* __restrict__ out, int n) {
  __shared__ ushort ts[32][136];
  __shared__ ushort Bs[48][136];
  __shared__ int eLds[SCAP];
  __shared__ float dLds[SCAP];
  __shared__ int pb[33];
  const int tid = threadIdx.x;
  const int row0 = blockIdx.x * 32;
#pragma unroll
  for (int q = 0; q < 2; ++q) {
    int f = tid + 512 * q;
    if (f < 768) {
      int r = f >> 4, cw = f & 15;
      *(uint4*)&Bs[r][cw * 8] = *(const uint4*)&Wtc[r * 128 + cw * 8];
    }
  }
  if (tid < 33) {
    int node = row0 + tid - 1;
    pb[tid] = (node < 0) ? 0 : P[node < n ? node : (n - 1)];
  }
  __syncthreads();
  const int sStart = pb[0];
  const int tot = pb[32] - sStart;
  const bool inL = (tot <= SCAP);
  if (inL) {
    for (int i = tid; i < tot; i += 512) {
      const int r = srcrow[sStart + i];
      eLds[i] = r;
      dLds[i] = dinv[r];
    }
  }
  __syncthreads();

  const int qid = tid >> 4;      // 32 quarters <-> 32 nodes (static)
  const int lq = tid & 15;
  const int c = row0 + qid;
  const int len = pb[qid + 1] - pb[qid];
  const int base = inL ? (pb[qid] - sStart) : pb[qid];
  const float dc = (c < n) ? dinv[c] : 0.f;

#pragma unroll
  for (int p = 0; p < 4; ++p) {
    const int coff = p * 32 + lq * 2;
    if (c < n) {
      const uint sv = *(const uint*)&xws[(size_t)c * 128 + coff];  // self
      const float bg0 = b_gcn[coff], bg1 = b_gcn[coff + 1];
      float a0 = 0.f, a1 = 0.f;
      int e = 0;
      if (inL) {
        for (; e + 4 <= len; e += 4) {
          const int r0 = eLds[base + e],     r1 = eLds[base + e + 1];
          const int r2 = eLds[base + e + 2], r3 = eLds[base + e + 3];
          const float d0 = dLds[base + e],     d1 = dLds[base + e + 1];
          const float d2 = dLds[base + e + 2], d3 = dLds[base + e + 3];
          const uint v0 = *(const uint*)&xws[(size_t)r0 * 128 + coff];
          const uint v1 = *(const uint*)&xws[(size_t)r1 * 128 + coff];
          const uint v2 = *(const uint*)&xws[(size_t)r2 * 128 + coff];
          const uint v3 = *(const uint*)&xws[(size_t)r3 * 128 + coff];
          a0 = fmaf(d0, b2f_lo(v0), a0); a1 = fmaf(d0, b2f_hi(v0), a1);
          a0 = fmaf(d1, b2f_lo(v1), a0); a1 = fmaf(d1, b2f_hi(v1), a1);
          a0 = fmaf(d2, b2f_lo(v2), a0); a1 = fmaf(d2, b2f_hi(v2), a1);
          a0 = fmaf(d3, b2f_lo(v3), a0); a1 = fmaf(d3, b2f_hi(v3), a1);
        }
        for (; e < len; ++e) {
          const int r = eLds[base + e];
          const float d = dLds[base + e];
          const uint v = *(const uint*)&xws[(size_t)r * 128 + coff];
          a0 = fmaf(d, b2f_lo(v), a0); a1 = fmaf(d, b2f_hi(v), a1);
        }
      } else {                           // fallback: global srcrow/dinv
        for (; e + 4 <= len; e += 4) {
          const int r0 = srcrow[base + e],     r1 = srcrow[base + e + 1];
          const int r2 = srcrow[base + e + 2], r3 = srcrow[base + e + 3];
          const float d0 = dinv[r0], d1 = dinv[r1];
          const float d2 = dinv[r2], d3 = dinv[r3];
          const uint v0 = *(const uint*)&xws[(size_t)r0 * 128 + coff];
          const uint v1 = *(const uint*)&xws[(size_t)r1 * 128 + coff];
          const uint v2 = *(const uint*)&xws[(size_t)r2 * 128 + coff];
          const uint v3 = *(const uint*)&xws[(size_t)r3 * 128 + coff];
          a0 = fmaf(d0, b2f_lo(v0), a0); a1 = fmaf(d0, b2f_hi(v0), a1);
          a0 = fmaf(d1, b2f_lo(v1), a0); a1 = fmaf(d1, b2f_hi(v1), a1);
          a0 = fmaf(d2, b2f_lo(v2), a0); a1 = fmaf(d2, b2f_hi(v2), a1);
          a0 = fmaf(d3, b2f_lo(v3), a0); a1 = fmaf(d3, b2f_hi(v3), a1);
        }
        for (; e < len; ++e) {
          const int r = srcrow[base + e];
          const float d = dinv[r];
          const uint v = *(const uint*)&xws[(size_t)r * 128 + coff];
          a0 = fmaf(d, b2f_lo(v), a0); a1 = fmaf(d, b2f_hi(v), a1);
        }
      }
      a0 = fmaf(dc, b2f_lo(sv), a0);     // self term
      a1 = fmaf(dc, b2f_hi(sv), a1);
      const float t0 = fmaxf(fmaf(dc, a0, bg0), 0.f);
      const float t1 = fmaxf(fmaf(dc, a1, bg1), 0.f);
      ushort2 o;
      o.x = f2b(t0);
      o.y = f2b(t1);
      *(ushort2*)&ts[qid][coff] = o;
    } else {
      *(ushort2*)&ts[qid][coff] = make_ushort2(0, 0);
    }
  }
  __syncthreads();

  // out = ts @ Wtc^T + bc : 2 row-blocks x 3 col-blocks = 6 MFMA tiles
  const int wid = tid >> 6, lane = tid & 63;
  if (wid < 6) {
    const int rb = wid & 1, nb = wid >> 1;
    const int fr = lane & 15, fg = lane >> 4;
    f32x4 acc = (f32x4){0.f, 0.f, 0.f, 0.f};
#pragma unroll
    for (int ks = 0; ks < 4; ++ks) {
      const int kb = ks * 32 + fg * 8;
      bf16x8 aa = *(const bf16x8*)&ts[rb * 16 + fr][kb];
      bf16x8 bb = *(const bf16x8*)&Bs[nb * 16 + fr][kb];
      acc = __builtin_amdgcn_mfma_f32_16x16x32_bf16(aa, bb, acc, 0, 0, 0);
    }
    const int cn = nb * 16 + fr;
    if (cn < 40) {
      const float bv = bc[cn];
      const int r0 = row0 + rb * 16 + fg * 4;
#pragma unroll
      for (int i = 0; i < 4; ++i) {
        const int rr = r0 + i;
        if (rr < n) out[(size_t)rr * 40 + cn] = acc[i] + bv;
      }
    }
  }
}

extern "C" void kernel_launch(void* const* d_in, const int* in_sizes, int n_in,
                              void* d_out, int out_size, void* d_ws, size_t ws_size,
                              hipStream_t stream) {
  const float* x     = (const float*)d_in[0];
  const int*   ei    = (const int*)d_in[1];
  const float* W_in  = (const float*)d_in[2];
  const float* b_in  = (const float*)d_in[3];
  const float* W_gcn = (const float*)d_in[4];
  const float* b_gcn = (const float*)d_in[5];
  const float* W_cls = (const float*)d_in[6];
  const float* b_cls = (const float*)d_in[7];
  float* out = (float*)d_out;

  const int N = in_sizes[0] / 128;
  const int E = in_sizes[1] / 2;
  const int* row = ei;
  const int* col = ei + E;

  const int sortb = (E + CH_MAX - 1) / CH_MAX;   // 128 for E=600000
  const int chunk = (E + sortb - 1) / sortb;      // <= CH_MAX
  const int nbuck = (N + 127) >> 7;               // 391
  const int NT    = (N + 127) >> 7;               // 128-row G12 tiles (391)
  const int T1    = NT / 3;                       // 130
  const int T2    = (2 * NT) / 3;                 // 260

  // d_ws layout (~18.6 MB)
  ushort* xws    = (ushort*)d_ws;                 // N*128 bf16
  ushort* Wti    = xws + (size_t)N * 128;         // 128x128
  ushort* Wtg    = Wti + 128 * 128;               // 128x128
  ushort* Wtc    = Wtg + 128 * 128;               // 48x128 zero-padded
  uint*   ebuf   = (uint*)(Wtc + 48 * 128);       // E
  int*    srcrow = (int*)(ebuf + E);              // E
  int*    H2     = srcrow + E;                    // NBUCK*sortb
  int*    Hs     = H2 + NBUCK * sortb;            // NBUCK+1
  int*    cursor = Hs + NBUCK + 1;                // NBUCK
  int*    P      = cursor + NBUCK;                // N
  float*  dinv   = (float*)(P + N);               // N

  // L1: weight prep || coarse chist
  k_L1_prep_chist<<<PREP_BLKS + sortb, 512, 0, stream>>>(
      W_in, W_gcn, W_cls, Wti, Wtg, Wtc, col, H2, E, chunk, sortb);

  // L2: bucket scan || G12 tiles [0, T1)
  k_L2_scan_g12<<<1 + T1, 512, 0, stream>>>(
      H2, Hs, cursor, sortb, x, Wti, Wtg, b_in, xws, N);

  // L3: reorder || G12 tiles [T1, T2)
  k_L3_reorder_g12<<<sortb + (T2 - T1), 512, 0, stream>>>(
      row, col, Hs, cursor, ebuf, E, chunk, sortb,
      x, Wti, Wtg, b_in, xws, N, T1);

  // L4: fine sort -> srcrow/P/dinv || G12 tiles [T2, NT)
  k_L4_sort_g12<<<nbuck + (NT - T2), 512, 0, stream>>>(
      ebuf, Hs, srcrow, P, dinv, nbuck, x, Wti, Wtg, b_in, xws, N, T2);

  // L5: out = relu(dinv[c]*(sum dinv[r]*xw[r] + dinv[c]*xw[c]) + b_gcn) @ W_cls + b_cls
  k_aggout<<<(N + 31) / 32, 512, 0, stream>>>(
      P, srcrow, xws, dinv, b_gcn, Wtc, b_cls, out, N);
}

// Round 18
// 77.498 us; speedup vs baseline: 1.1247x; 1.1247x over previous
//
#include <hip/hip_runtime.h>

// ---------------------------------------------------------------------------
// PYG_GCN: y = relu(x@W_in+b_in) -> GCNConv(W_gcn,b_gcn) -> relu -> @W_cls+b_cls
// N=50000, E=600000, D=128, C=40.
// R18 = exact revert to R15 (session best, 77.3us). R16 (deeper MLP) and R17
// (column-sliced L2 gather) both failed to beat it -> gather is at its
// random-access service floor; pipeline is overlap-saturated.
//   L1 prep||chist -> L2 scan||G12a -> L3 reorder||G12b -> L4 sort2||G12c
//   -> L5 aggout
// ---------------------------------------------------------------------------

typedef __bf16 bf16x8 __attribute__((ext_vector_type(8)));
typedef float f32x4 __attribute__((ext_vector_type(4)));

#define NBUCK 512      // bucket = col>>7; used 0..390 for N=50000
#define CH_MAX 4704    // max edges per sort-chunk block
#define PREP_BLKS 76   // 38912 weight elements / 512
#define SCAP 1024      // aggout LDS edge window (32 nodes: mean 384)

__device__ __forceinline__ ushort f2b(float f) {  // fp32 -> bf16 RNE
  uint u = __float_as_uint(f);
  return (ushort)((u + 0x7FFFu + ((u >> 16) & 1u)) >> 16);
}
__device__ __forceinline__ float b2f_lo(uint u) { return __uint_as_float(u << 16); }
__device__ __forceinline__ float b2f_hi(uint u) { return __uint_as_float(u & 0xFFFF0000u); }

__device__ __forceinline__ void acc8s(float* a, uint4 v, float d) {
  a[0] = fmaf(d, b2f_lo(v.x), a[0]); a[1] = fmaf(d, b2f_hi(v.x), a[1]);
  a[2] = fmaf(d, b2f_lo(v.y), a[2]); a[3] = fmaf(d, b2f_hi(v.y), a[3]);
  a[4] = fmaf(d, b2f_lo(v.z), a[4]); a[5] = fmaf(d, b2f_hi(v.z), a[5]);
  a[6] = fmaf(d, b2f_lo(v.w), a[6]); a[7] = fmaf(d, b2f_hi(v.w), a[7]);
}

// ---------------- fused GEMM1+2 tile: 512 threads, 128 rows ----------------
// xws = (relu(x@Wti^T + b_in)) @ Wtg^T   (h lives only in LDS; unscaled out)
__device__ __forceinline__ void g12_tile_512(const float* __restrict__ x,
                                             const ushort* __restrict__ Wti,
                                             const ushort* __restrict__ Wtg,
                                             const float* __restrict__ b_in,
                                             ushort* __restrict__ xws,
                                             int nrows, int row0,
                                             char* smem, int tid) {
  ushort (*As)[136] = (ushort(*)[136])smem;                    // 128 rows
  ushort (*Bs)[136] = (ushort(*)[136])(smem + 128 * 136 * 2);  // 128 rows
#pragma unroll
  for (int q = 0; q < 4; ++q) {
    int f = tid + 512 * q;
    int r = f >> 4, cw = f & 15;
    *(uint4*)&Bs[r][cw * 8] = *(const uint4*)&Wti[r * 128 + cw * 8];
  }
#pragma unroll
  for (int q = 0; q < 8; ++q) {
    int f = tid + 512 * q;
    int r = f >> 5, kc = f & 31;
    float4 v = make_float4(0.f, 0.f, 0.f, 0.f);
    if (row0 + r < nrows) v = *(const float4*)&x[(size_t)(row0 + r) * 128 + kc * 4];
    ushort4 o;
    o.x = f2b(v.x); o.y = f2b(v.y); o.z = f2b(v.z); o.w = f2b(v.w);
    *(ushort4*)&As[r][kc * 4] = o;
  }
  __syncthreads();

  const int wid = tid >> 6, lane = tid & 63;
  const int fr = lane & 15, fg = lane >> 4;
  f32x4 acc[8];
#pragma unroll
  for (int nn = 0; nn < 8; ++nn) acc[nn] = (f32x4){0.f, 0.f, 0.f, 0.f};
#pragma unroll
  for (int ks = 0; ks < 4; ++ks) {
    const int kb = ks * 32 + fg * 8;
    bf16x8 a = *(const bf16x8*)&As[wid * 16 + fr][kb];
#pragma unroll
    for (int nn = 0; nn < 8; ++nn) {
      bf16x8 b = *(const bf16x8*)&Bs[nn * 16 + fr][kb];
      acc[nn] = __builtin_amdgcn_mfma_f32_16x16x32_bf16(a, b, acc[nn], 0, 0, 0);
    }
  }
  __syncthreads();  // all stage-1 reads done

  // h = relu(acc + b_in) -> bf16 back into As (D-frag layout); restage Wtg
#pragma unroll
  for (int nn = 0; nn < 8; ++nn) {
    const int cn = nn * 16 + fr;
    const float bv = b_in[cn];
#pragma unroll
    for (int i = 0; i < 4; ++i)
      As[wid * 16 + fg * 4 + i][cn] = f2b(fmaxf(acc[nn][i] + bv, 0.f));
  }
#pragma unroll
  for (int q = 0; q < 4; ++q) {
    int f = tid + 512 * q;
    int r = f >> 4, cw = f & 15;
    *(uint4*)&Bs[r][cw * 8] = *(const uint4*)&Wtg[r * 128 + cw * 8];
  }
  __syncthreads();

  f32x4 acc2[8];
#pragma unroll
  for (int nn = 0; nn < 8; ++nn) acc2[nn] = (f32x4){0.f, 0.f, 0.f, 0.f};
#pragma unroll
  for (int ks = 0; ks < 4; ++ks) {
    const int kb = ks * 32 + fg * 8;
    bf16x8 a = *(const bf16x8*)&As[wid * 16 + fr][kb];
#pragma unroll
    for (int nn = 0; nn < 8; ++nn) {
      bf16x8 b = *(const bf16x8*)&Bs[nn * 16 + fr][kb];
      acc2[nn] = __builtin_amdgcn_mfma_f32_16x16x32_bf16(a, b, acc2[nn], 0, 0, 0);
    }
  }
  const int r0 = row0 + wid * 16 + fg * 4;
#pragma unroll
  for (int nn = 0; nn < 8; ++nn) {
    const int cn = nn * 16 + fr;
#pragma unroll
    for (int i = 0; i < 4; ++i) {
      const int rr = r0 + i;
      if (rr < nrows) xws[(size_t)rr * 128 + cn] = f2b(acc2[nn][i]);
    }
  }
}

// ---------------- L1: weight prep [0,76) || coarse chist -------------------
__global__ __launch_bounds__(512) void k_L1_prep_chist(const float* __restrict__ Wi,
                                                       const float* __restrict__ Wg,
                                                       const float* __restrict__ Wc,
                                                       ushort* __restrict__ Ti,
                                                       ushort* __restrict__ Tg,
                                                       ushort* __restrict__ Tc,
                                                       const int* __restrict__ col,
                                                       int* __restrict__ H2,
                                                       int E, int chunk, int sortb) {
  __shared__ int hist[NBUCK];
  const int tid = threadIdx.x;
  if (blockIdx.x < PREP_BLKS) {
    int idx = blockIdx.x * 512 + tid;
    if (idx < 16384) {
      int c = idx >> 7, k = idx & 127;
      Ti[c * 128 + k] = f2b(Wi[k * 128 + c]);
    } else if (idx < 32768) {
      int j = idx - 16384;
      int c = j >> 7, k = j & 127;
      Tg[c * 128 + k] = f2b(Wg[k * 128 + c]);
    } else if (idx < 38912) {
      int j = idx - 32768;
      int c = j >> 7, k = j & 127;
      Tc[c * 128 + k] = (c < 40) ? f2b(Wc[k * 40 + c]) : (ushort)0;
    }
    return;
  }
  const int blk = blockIdx.x - PREP_BLKS;
  if (tid < NBUCK) hist[tid] = 0;
  __syncthreads();
  const int e0 = blk * chunk;
  const int cnt = min(chunk, E - e0);
  for (int i = tid; i < cnt; i += 512)
    atomicAdd(&hist[((unsigned)col[e0 + i]) >> 7], 1);
  __syncthreads();
  if (tid < NBUCK) H2[tid * sortb + blk] = hist[tid];
}

// ---------------- L2: block 0 = bucket scan; blocks 1.. = G12 tiles [0,T1) -
__global__ __launch_bounds__(512) void k_L2_scan_g12(const int* __restrict__ H2,
                                                     int* __restrict__ Hs,
                                                     int* __restrict__ cursor,
                                                     int sortb,
                                                     const float* __restrict__ x,
                                                     const ushort* __restrict__ Wti,
                                                     const ushort* __restrict__ Wtg,
                                                     const float* __restrict__ b_in,
                                                     ushort* __restrict__ xws,
                                                     int nrows) {
  __shared__ __align__(16) char smem[69632];
  const int tid = threadIdx.x;
  if (blockIdx.x == 0) {
    int* sd = (int*)smem;  // 512 ints
    int s = 0;
    const int4* p = (const int4*)&H2[tid * sortb];
    for (int j = 0; j < sortb / 4; ++j) { int4 v = p[j]; s += v.x + v.y + v.z + v.w; }
    sd[tid] = s;
    __syncthreads();
    for (int off = 1; off < 512; off <<= 1) {
      int u = (tid >= off) ? sd[tid - off] : 0;
      __syncthreads();
      sd[tid] += u;
      __syncthreads();
    }
    Hs[tid] = sd[tid] - s;          // exclusive
    if (tid == 511) Hs[NBUCK] = sd[511];
    cursor[tid] = 0;
    return;
  }
  g12_tile_512(x, Wti, Wtg, b_in, xws, nrows, (blockIdx.x - 1) * 128, smem, tid);
}

// ---------------- L3: reorder [0,sortb) || G12 tiles [T1,T2) ---------------
// ebuf record: (c_local<<16) | row  (row < 65536 since N=50000).
__global__ __launch_bounds__(512) void k_L3_reorder_g12(const int* __restrict__ row,
                                                        const int* __restrict__ col,
                                                        const int* __restrict__ Hs,
                                                        int* __restrict__ cursor,
                                                        uint* __restrict__ ebuf,
                                                        int E, int chunk, int sortb,
                                                        const float* __restrict__ x,
                                                        const ushort* __restrict__ Wti,
                                                        const ushort* __restrict__ Wtg,
                                                        const float* __restrict__ b_in,
                                                        ushort* __restrict__ xws,
                                                        int nrows, int tile0) {
  __shared__ __align__(16) char smem[69632];
  const int tid = threadIdx.x;
  if (blockIdx.x < (unsigned)sortb) {
    int* hist   = (int*)smem;              // NBUCK
    int* lstart = hist + NBUCK;            // NBUCK
    int* cnt2   = lstart + NBUCK;          // NBUCK
    int* obase  = cnt2 + NBUCK;            // NBUCK
    uint* data  = (uint*)(obase + NBUCK);  // CH_MAX
    int* gpos   = (int*)(data + CH_MAX);   // CH_MAX
    int* sd     = gpos + CH_MAX;           // 512
    hist[tid] = 0; cnt2[tid] = 0;
    __syncthreads();
    const int e0 = blockIdx.x * chunk;
    const int cnt = min(chunk, E - e0);
    for (int i = tid; i < cnt; i += 512)
      atomicAdd(&hist[((unsigned)col[e0 + i]) >> 7], 1);
    __syncthreads();
    const int h0 = hist[tid];
    sd[tid] = h0;
    __syncthreads();
    for (int off = 1; off < 512; off <<= 1) {
      int u = (tid >= off) ? sd[tid - off] : 0;
      __syncthreads();
      sd[tid] += u;
      __syncthreads();
    }
    lstart[tid] = sd[tid] - h0;
    obase[tid] = Hs[tid] + (h0 ? atomicAdd(&cursor[tid], h0) : 0);
    __syncthreads();
    for (int i = tid; i < cnt; i += 512) {
      const int c = col[e0 + i], r = row[e0 + i];
      const int b = ((unsigned)c) >> 7;
      const int rk = atomicAdd(&cnt2[b], 1);
      const int slot = lstart[b] + rk;
      data[slot] = ((uint)(c & 127) << 16) | (uint)r;
      gpos[slot] = obase[b] + rk;
    }
    __syncthreads();
    for (int i = tid; i < cnt; i += 512)
      ebuf[gpos[i]] = data[i];
    return;
  }
  g12_tile_512(x, Wti, Wtg, b_in, xws, nrows,
               (tile0 + (int)blockIdx.x - sortb) * 128, smem, tid);
}

// ---------------- L4: sort2 [0,nbuck) || G12 tiles [T2,NT) -----------------
// P[node] = END offset (seg = [P[c-1], P[c]), P[-1] := 0).
__global__ __launch_bounds__(512) void k_L4_sort_g12(const uint* __restrict__ ebuf,
                                                     const int* __restrict__ Hs,
                                                     int* __restrict__ srcrow,
                                                     int* __restrict__ P,
                                                     float* __restrict__ dinv,
                                                     int nbuck,
                                                     const float* __restrict__ x,
                                                     const ushort* __restrict__ Wti,
                                                     const ushort* __restrict__ Wtg,
                                                     const float* __restrict__ b_in,
                                                     ushort* __restrict__ xws,
                                                     int n, int tile0) {
  __shared__ __align__(16) char smem[69632];
  const int tid = threadIdx.x;
  if (blockIdx.x < (unsigned)nbuck) {
    int* cnt    = (int*)smem;        // 128
    int* lstart = cnt + 128;         // 128
    int* cnt2   = lstart + 128;      // 128
    int* sd     = cnt2 + 128;        // 512
    if (tid < 128) { cnt[tid] = 0; cnt2[tid] = 0; }
    __syncthreads();
    const int b = blockIdx.x;
    const int start = Hs[b];
    const int end = Hs[b + 1];
    for (int i = start + tid; i < end; i += 512)
      atomicAdd(&cnt[ebuf[i] >> 16], 1);
    __syncthreads();
    const int cv = (tid < 128) ? cnt[tid] : 0;
    sd[tid] = cv;
    __syncthreads();
    for (int off = 1; off < 128; off <<= 1) {
      int u = (tid >= off) ? sd[tid - off] : 0;
      __syncthreads();
      sd[tid] += u;
      __syncthreads();
    }
    if (tid < 128) {
      const int ex = sd[tid] - cv;
      lstart[tid] = ex;
      const int node = b * 128 + tid;
      if (node < n) {
        P[node] = start + ex + cv;
        dinv[node] = rsqrtf((float)cv + 1.0f);
      }
    }
    __syncthreads();
    for (int i = start + tid; i < end; i += 512) {
      const uint v = ebuf[i];
      const int c = v >> 16;
      const int rk = atomicAdd(&cnt2[c], 1);
      srcrow[start + lstart[c] + rk] = (int)(v & 0xFFFFu);
    }
    return;
  }
  g12_tile_512(x, Wti, Wtg, b_in, xws, n,
               (tile0 + (int)blockIdx.x - nbuck) * 128, smem, tid);
}

// ---------------- L5: fused aggregate + classifier -------------------------
// 512 threads / 32 nodes. Quarter-per-node gather: each 16-lane quarter owns
// one node (full 128-col row via lane-uint4); 4 node streams per wave, no
// cross-lane reduce. srcrow window + P boundaries staged in LDS.
__global__ __launch_bounds__(512) void k_aggout(const int* __restrict__ P,
                                                const int* __restrict__ srcrow,
                                                const ushort* __restrict__ xws,
                                                const float* __restrict__ dinv,
                                                const float* __restrict__ b_gcn,
                                                const ushort* __restrict__ Wtc,
                                                const float* __restrict__ bc,
                                                float* __restrict__ out, int n) {
  __shared__ ushort ts[32][136];
  __shared__ ushort Bs[48][136];
  __shared__ int eLds[SCAP];
  __shared__ int pb[33];
  __shared__ int nextn;
  const int tid = threadIdx.x;
  const int row0 = blockIdx.x * 32;
#pragma unroll
  for (int q = 0; q < 2; ++q) {
    int f = tid + 512 * q;
    if (f < 768) {
      int r = f >> 4, cw = f & 15;
      *(uint4*)&Bs[r][cw * 8] = *(const uint4*)&Wtc[r * 128 + cw * 8];
    }
  }
  if (tid < 33) {
    int node = row0 + tid - 1;
    pb[tid] = (node < 0) ? 0 : P[node < n ? node : (n - 1)];
  }
  if (tid == 0) nextn = 0;
  __syncthreads();
  const int sStart = pb[0];
  const int tot = pb[32] - sStart;
  const bool inL = (tot <= SCAP);
  if (inL) {
    for (int i = tid; i < tot; i += 512) eLds[i] = srcrow[sStart + i];
  }
  __syncthreads();

  const int wid = tid >> 6, lane = tid & 63;
  const int lq = lane & 15;                   // lane in quarter
  const size_t coff = (size_t)lq * 8;         // 8 cols per lane

  float bg[8];
#pragma unroll
  for (int j = 0; j < 8; ++j) bg[j] = b_gcn[lq * 8 + j];

  // quarter-per-node dynamic queue
  for (;;) {
    int idx;
    if (lq == 0) idx = atomicAdd(&nextn, 1);
    idx = __shfl(idx, lane & 48);   // broadcast within quarter
    if (idx >= 32) break;
    const int c = row0 + idx;
    if (c < n) {
      const int len = pb[idx + 1] - pb[idx];
      float a[8];
#pragma unroll
      for (int j = 0; j < 8; ++j) a[j] = 0.f;
      if (inL) {
        const int base = pb[idx] - sStart;
        int e = 0;
        for (; e + 2 <= len; e += 2) {
          const int r0 = eLds[base + e], r1 = eLds[base + e + 1];
          const float d0 = dinv[r0], d1 = dinv[r1];
          const uint4 v0 = *(const uint4*)&xws[(size_t)r0 * 128 + coff];
          const uint4 v1 = *(const uint4*)&xws[(size_t)r1 * 128 + coff];
          acc8s(a, v0, d0);
          acc8s(a, v1, d1);
        }
        if (e < len) {
          const int r = eLds[base + e];
          const float d = dinv[r];
          const uint4 v = *(const uint4*)&xws[(size_t)r * 128 + coff];
          acc8s(a, v, d);
        }
      } else {
        const int base = pb[idx];
        int e = 0;
        for (; e + 2 <= len; e += 2) {
          const int r0 = srcrow[base + e], r1 = srcrow[base + e + 1];
          const float d0 = dinv[r0], d1 = dinv[r1];
          const uint4 v0 = *(const uint4*)&xws[(size_t)r0 * 128 + coff];
          const uint4 v1 = *(const uint4*)&xws[(size_t)r1 * 128 + coff];
          acc8s(a, v0, d0);
          acc8s(a, v1, d1);
        }
        if (e < len) {
          const int r = srcrow[base + e];
          const float d = dinv[r];
          const uint4 v = *(const uint4*)&xws[(size_t)r * 128 + coff];
          acc8s(a, v, d);
        }
      }
      const uint4 sv = *(const uint4*)&xws[(size_t)c * 128 + coff];  // self
      const float dc = dinv[c];
      acc8s(a, sv, dc);
      const float t0 = fmaxf(fmaf(dc, a[0], bg[0]), 0.f);
      const float t1 = fmaxf(fmaf(dc, a[1], bg[1]), 0.f);
      const float t2 = fmaxf(fmaf(dc, a[2], bg[2]), 0.f);
      const float t3 = fmaxf(fmaf(dc, a[3], bg[3]), 0.f);
      const float t4 = fmaxf(fmaf(dc, a[4], bg[4]), 0.f);
      const float t5 = fmaxf(fmaf(dc, a[5], bg[5]), 0.f);
      const float t6 = fmaxf(fmaf(dc, a[6], bg[6]), 0.f);
      const float t7 = fmaxf(fmaf(dc, a[7], bg[7]), 0.f);
      uint4 o;
      o.x = ((uint)f2b(t1) << 16) | f2b(t0);
      o.y = ((uint)f2b(t3) << 16) | f2b(t2);
      o.z = ((uint)f2b(t5) << 16) | f2b(t4);
      o.w = ((uint)f2b(t7) << 16) | f2b(t6);
      *(uint4*)&ts[idx][coff] = o;
    } else {
      *(uint4*)&ts[idx][coff] = make_uint4(0u, 0u, 0u, 0u);
    }
  }
  __syncthreads();

  // out = ts @ Wtc^T + bc : 2 row-blocks x 3 col-blocks = 6 MFMA tiles
  if (wid < 6) {
    const int rb = wid & 1, nb = wid >> 1;
    const int fr = lane & 15, fg = lane >> 4;
    f32x4 acc = (f32x4){0.f, 0.f, 0.f, 0.f};
#pragma unroll
    for (int ks = 0; ks < 4; ++ks) {
      const int kb = ks * 32 + fg * 8;
      bf16x8 aa = *(const bf16x8*)&ts[rb * 16 + fr][kb];
      bf16x8 bb = *(const bf16x8*)&Bs[nb * 16 + fr][kb];
      acc = __builtin_amdgcn_mfma_f32_16x16x32_bf16(aa, bb, acc, 0, 0, 0);
    }
    const int cn = nb * 16 + fr;
    if (cn < 40) {
      const float bv = bc[cn];
      const int r0 = row0 + rb * 16 + fg * 4;
#pragma unroll
      for (int i = 0; i < 4; ++i) {
        const int rr = r0 + i;
        if (rr < n) out[(size_t)rr * 40 + cn] = acc[i] + bv;
      }
    }
  }
}

extern "C" void kernel_launch(void* const* d_in, const int* in_sizes, int n_in,
                              void* d_out, int out_size, void* d_ws, size_t ws_size,
                              hipStream_t stream) {
  const float* x     = (const float*)d_in[0];
  const int*   ei    = (const int*)d_in[1];
  const float* W_in  = (const float*)d_in[2];
  const float* b_in  = (const float*)d_in[3];
  const float* W_gcn = (const float*)d_in[4];
  const float* b_gcn = (const float*)d_in[5];
  const float* W_cls = (const float*)d_in[6];
  const float* b_cls = (const float*)d_in[7];
  float* out = (float*)d_out;

  const int N = in_sizes[0] / 128;
  const int E = in_sizes[1] / 2;
  const int* row = ei;
  const int* col = ei + E;

  const int sortb = (E + CH_MAX - 1) / CH_MAX;   // 128 for E=600000
  const int chunk = (E + sortb - 1) / sortb;      // <= CH_MAX
  const int nbuck = (N + 127) >> 7;               // 391
  const int NT    = (N + 127) >> 7;               // 128-row G12 tiles (391)
  const int T1    = NT / 3;                       // 130
  const int T2    = (2 * NT) / 3;                 // 260

  // d_ws layout (~18.6 MB)
  ushort* xws    = (ushort*)d_ws;                 // N*128 bf16
  ushort* Wti    = xws + (size_t)N * 128;         // 128x128
  ushort* Wtg    = Wti + 128 * 128;               // 128x128
  ushort* Wtc    = Wtg + 128 * 128;               // 48x128 zero-padded
  uint*   ebuf   = (uint*)(Wtc + 48 * 128);       // E
  int*    srcrow = (int*)(ebuf + E);              // E
  int*    H2     = srcrow + E;                    // NBUCK*sortb
  int*    Hs     = H2 + NBUCK * sortb;            // NBUCK+1
  int*    cursor = Hs + NBUCK + 1;                // NBUCK
  int*    P      = cursor + NBUCK;                // N
  float*  dinv   = (float*)(P + N);               // N

  // L1: weight prep || coarse chist
  k_L1_prep_chist<<<PREP_BLKS + sortb, 512, 0, stream>>>(
      W_in, W_gcn, W_cls, Wti, Wtg, Wtc, col, H2, E, chunk, sortb);

  // L2: bucket scan || G12 tiles [0, T1)
  k_L2_scan_g12<<<1 + T1, 512, 0, stream>>>(
      H2, Hs, cursor, sortb, x, Wti, Wtg, b_in, xws, N);

  // L3: reorder || G12 tiles [T1, T2)
  k_L3_reorder_g12<<<sortb + (T2 - T1), 512, 0, stream>>>(
      row, col, Hs, cursor, ebuf, E, chunk, sortb,
      x, Wti, Wtg, b_in, xws, N, T1);

  // L4: fine sort -> srcrow/P/dinv || G12 tiles [T2, NT)
  k_L4_sort_g12<<<nbuck + (NT - T2), 512, 0, stream>>>(
      ebuf, Hs, srcrow, P, dinv, nbuck, x, Wti, Wtg, b_in, xws, N, T2);

  // L5: out = relu(dinv[c]*(sum dinv[r]*xw[r] + dinv[c]*xw[c]) + b_gcn) @ W_cls + b_cls
  k_aggout<<<(N + 31) / 32, 512, 0, stream>>>(
      P, srcrow, xws, dinv, b_gcn, Wtc, b_cls, out, N);
}